// Round 6
// baseline (505.100 us; speedup 1.0000x reference)
//
#include <hip/hip_runtime.h>
#include <stdint.h>

#define NN 16384
#define EE 262144
#define DD 256

typedef float f32x4 __attribute__((ext_vector_type(4)));
typedef float f32x2 __attribute__((ext_vector_type(2)));
typedef short s16x8 __attribute__((ext_vector_type(8)));
typedef unsigned short u16x4 __attribute__((ext_vector_type(4)));
typedef unsigned short u16x8 __attribute__((ext_vector_type(8)));

#define AS1 __attribute__((address_space(1)))
#define AS3 __attribute__((address_space(3)))

__device__ __forceinline__ float bf2f(unsigned short u) {
  union { unsigned int i; float f; } v; v.i = ((unsigned int)u) << 16; return v.f;
}
__device__ __forceinline__ unsigned short f2bf(float f) {
  union { float f; unsigned int i; } v; v.f = f;
  unsigned int r = v.i + 0x7fffu + ((v.i >> 16) & 1u);
  return (unsigned short)(r >> 16);
}
__device__ __forceinline__ float lrelu(float x) { return x > 0.f ? x : 0.2f * x; }

// ---- OCP e4m3fn helpers (subnormals flushed; |x|>=448 clamps to 448) ----
__device__ __forceinline__ uint8_t f2e4m3(float x) {
  uint32_t xu = __float_as_uint(x);
  uint32_t s = (xu >> 24) & 0x80u;
  float a = fabsf(x);
  if (a >= 448.f) return (uint8_t)(s | 0x7Eu);
  if (a < 0.015625f) return (uint8_t)s;
  uint32_t u = xu & 0x7FFFFFFFu;
  u = u + 0x0007FFFFu + ((u >> 20) & 1u);   // RNE to 3-bit mantissa
  uint32_t E = (u >> 23) - 120u;            // exp-127+7
  if (E >= 16u) return (uint8_t)(s | 0x7Eu);
  return (uint8_t)(s | (E << 3) | ((u >> 20) & 7u));
}
__device__ __forceinline__ float e4m3f(uint32_t b) {
  uint32_t ex = b & 0x78u;
  uint32_t bits = ((b & 0x80u) << 24) | (((b & 0x7fu) << 20) + (120u << 23));
  union { uint32_t u; float f; } v;
  v.u = ex ? bits : ((b & 0x80u) << 24);
  return v.f;
}
#if defined(__has_builtin)
#if __has_builtin(__builtin_amdgcn_cvt_pk_f32_fp8)
#define HAVE_CVT_FP8 1
#endif
#endif
__device__ __forceinline__ void dec4(uint32_t w, float* f) {
#ifdef HAVE_CVT_FP8
  f32x2 lo = __builtin_amdgcn_cvt_pk_f32_fp8(w, false);
  f32x2 hi = __builtin_amdgcn_cvt_pk_f32_fp8(w, true);
  f[0] = lo[0]; f[1] = lo[1]; f[2] = hi[0]; f[3] = hi[1];
#else
  f[0] = e4m3f(w & 0xFFu); f[1] = e4m3f((w >> 8) & 0xFFu);
  f[2] = e4m3f((w >> 16) & 0xFFu); f[3] = e4m3f(w >> 24);
#endif
}
__device__ __forceinline__ void dec16(uint4 v, float* f) {
  dec4(v.x, f); dec4(v.y, f + 4); dec4(v.z, f + 8); dec4(v.w, f + 12);
}

// channel-storage permutation (involution): swap ct<->quad fields so each
// lane's 16 MFMA accumulator channels are 16 CONTIGUOUS Qa/Ka columns.
__device__ __forceinline__ int chanperm(int c) {
  int hi = c & ~63, loc = c & 63;
  int ct = loc >> 4, quad = (loc >> 2) & 3, rr = loc & 3;
  return hi | (quad * 16 + ct * 4 + rr);
}

// ---------------------------------------------------------------------------
// K1 = prep (weight algebra, blocks 0..706) + src-degree hist (707..1730).
// ---------------------------------------------------------------------------
__global__ __launch_bounds__(256) void prep_hist_kernel(
    const float* __restrict__ Wn, const float* __restrict__ bn,
    const float* __restrict__ Wq, const float* __restrict__ bq,
    const float* __restrict__ Wk, const float* __restrict__ bk,
    const float* __restrict__ Wv, const float* __restrict__ bv,
    const float* __restrict__ We, const float* __restrict__ be,
    const float* __restrict__ A1, const float* __restrict__ a1,
    const float* __restrict__ A2, const int* __restrict__ eidx,
    unsigned short* __restrict__ BcatT, float* __restrict__ bcat,
    unsigned short* __restrict__ WeaT, float* __restrict__ bcomb,
    float* __restrict__ A2p, int* __restrict__ deg)
{
  const int b = blockIdx.x, t = threadIdx.x;
  if (b < 256) {                 // Wqa
    float acc = 0.f;
    for (int j = 0; j < 256; ++j) acc += Wq[b * 256 + j] * A1[j * 256 + t];
    BcatT[(512 + t) * 256 + b] = f2bf(acc);
  } else if (b < 512) {          // Wka
    int k = b - 256; float acc = 0.f;
    for (int j = 0; j < 256; ++j) acc += Wk[k * 256 + j] * A1[(256 + j) * 256 + t];
    BcatT[(768 + t) * 256 + k] = f2bf(acc);
  } else if (b < 576) {          // WeaT row chanperm(t), col k = b-512
    int k = b - 512; float acc = 0.f;
    for (int j = 0; j < 256; ++j) acc += We[k * 256 + j] * A1[(512 + j) * 256 + t];
    WeaT[chanperm(t) * 64 + k] = f2bf(acc);
  } else if (b == 576) {         // bcomb (storage order)
    float acc = a1[t];
    for (int j = 0; j < 256; ++j) {
      acc += bq[j] * A1[j * 256 + t];
      acc += bk[j] * A1[(256 + j) * 256 + t];
      acc += be[j] * A1[(512 + j) * 256 + t];
    }
    bcomb[chanperm(t)] = acc;
  } else if (b < 705) {          // transpose Wn, Wv into BcatT rows 0..511
    int b2 = b - 577;
    for (int rr = 0; rr < 4; ++rr) {
      int np = b2 * 4 + rr;
      float v = (np < 256) ? Wn[t * 256 + np] : Wv[t * 256 + (np - 256)];
      BcatT[np * 256 + t] = f2bf(v);
    }
  } else if (b == 705) {         // bcat
    bcat[t] = bn[t];
    bcat[256 + t] = bv[t];
    bcat[512 + t] = 0.f;
    bcat[768 + t] = 0.f;
  } else if (b == 706) {         // A2p (storage order)
    int m = chanperm(t);
    for (int j = 0; j < 8; ++j) A2p[m * 8 + j] = A2[t * 8 + j];
  } else {                       // hist
    int e = (b - 707) * 256 + t;
    atomicAdd(&deg[eidx[e]], 1);
  }
}

// ---------------------------------------------------------------------------
// K2 = nf f32->bf16 conversion (blocks 0..2047) + CSR scan (block 2048).
// ---------------------------------------------------------------------------
__global__ __launch_bounds__(256) void conv_scan_kernel(
    const float* __restrict__ in, unsigned short* __restrict__ o,
    const int* __restrict__ deg, int* __restrict__ startA,
    int* __restrict__ cursor)
{
  const int t = threadIdx.x;
  if (blockIdx.x < 2048) {
    size_t i = (size_t)blockIdx.x * 256 + t;
    const f32x4* p = (const f32x4*)(in + i * 8);
    f32x4 a = p[0], b = p[1];
    u16x8 r = { f2bf(a[0]), f2bf(a[1]), f2bf(a[2]), f2bf(a[3]),
                f2bf(b[0]), f2bf(b[1]), f2bf(b[2]), f2bf(b[3]) };
    *(u16x8*)(o + i * 8) = r;
    return;
  }
  __shared__ int ls[256];
  int4 d[16];
  int s = 0;
  #pragma unroll
  for (int i = 0; i < 16; ++i) {
    d[i] = ((const int4*)deg)[t * 16 + i];
    s += d[i].x + d[i].y + d[i].z + d[i].w;
  }
  ls[t] = s;
  __syncthreads();
  for (int dd = 1; dd < 256; dd <<= 1) {
    int v = ls[t];
    if (t >= dd) v += ls[t - dd];
    __syncthreads();
    ls[t] = v;
    __syncthreads();
  }
  int run = ls[t] - s;
  #pragma unroll
  for (int i = 0; i < 16; ++i) {
    int4 ov;
    ov.x = run; run += d[i].x;
    ov.y = run; run += d[i].y;
    ov.z = run; run += d[i].z;
    ov.w = run; run += d[i].w;
    ((int4*)startA)[t * 16 + i] = ov;
    ((int4*)cursor)[t * 16 + i] = ov;
  }
  if (t == 255) startA[NN] = run;
}

// ---------------------------------------------------------------------------
// K3 = perm scatter (blocks 0..1023) + node GEMM (1024..2047).
// GEMM out: h bf16, v/Qa/Ka fp8 e4m3.  perm writes st2 = (src,tgt) pairs.
// ---------------------------------------------------------------------------
__global__ __launch_bounds__(256, 1) void gemm_perm_kernel(
    const unsigned short* __restrict__ Abf,
    const unsigned short* __restrict__ BT,
    const float* __restrict__ bias,
    unsigned short* __restrict__ hout, uint8_t* __restrict__ vq,
    uint8_t* __restrict__ Qaq, uint8_t* __restrict__ Kaq,
    const int* __restrict__ eidx, int* __restrict__ cursor,
    int* __restrict__ perm, int2* __restrict__ st2)
{
  const int t = threadIdx.x;
  if (blockIdx.x < 1024) {       // perm part
    int e = blockIdx.x * 256 + t;
    int s = eidx[e], tg = eidx[EE + e];
    int pos = atomicAdd(&cursor[s], 1);
    perm[pos] = e;
    st2[pos] = make_int2(s, tg);
    return;
  }
  __shared__ __align__(16) unsigned short Al[128 * 64];
  __shared__ __align__(16) unsigned short Bl[128 * 64];
  const int b2 = blockIdx.x - 1024;
  const int wid = t >> 6, lane = t & 63;
  const int quad = lane >> 4, l15 = lane & 15;
  const int mblk = b2 & 127, nblk = b2 >> 7;
  const int m0 = mblk * 128, n0 = nblk * 128;
  const int mh = wid >> 1, nh = wid & 1;
  const int srow = lane >> 3, sslot = lane & 7;

  f32x4 acc[4][4];
  #pragma unroll
  for (int i = 0; i < 4; ++i)
    #pragma unroll
    for (int j = 0; j < 4; ++j) acc[i][j] = (f32x4){0.f, 0.f, 0.f, 0.f};

  for (int ks = 0; ks < 4; ++ks) {
    const int k0 = ks * 64;
    #pragma unroll
    for (int j = 0; j < 4; ++j) {
      int cj = wid * 4 + j;
      int row = cj * 8 + srow;
      const unsigned short* ga =
          Abf + (size_t)(m0 + row) * 256 + k0 + ((sslot ^ (row & 7)) * 8);
      __builtin_amdgcn_global_load_lds((AS1 const void*)ga,
                                       (AS3 void*)(Al + cj * 512), 16, 0, 0);
      const unsigned short* gb =
          BT + (size_t)(n0 + row) * 256 + k0 + ((sslot ^ (row & 7)) * 8);
      __builtin_amdgcn_global_load_lds((AS1 const void*)gb,
                                       (AS3 void*)(Bl + cj * 512), 16, 0, 0);
    }
    __syncthreads();
    s16x8 af[4][2], bfr[4][2];
    #pragma unroll
    for (int mt = 0; mt < 4; ++mt) {
      int row = mh * 64 + mt * 16 + l15;
      #pragma unroll
      for (int kk = 0; kk < 2; ++kk) {
        int s = (kk * 4 + quad) ^ (row & 7);
        af[mt][kk] = *(const s16x8*)(Al + row * 64 + s * 8);
      }
    }
    #pragma unroll
    for (int nt = 0; nt < 4; ++nt) {
      int row = nh * 64 + nt * 16 + l15;
      #pragma unroll
      for (int kk = 0; kk < 2; ++kk) {
        int s = (kk * 4 + quad) ^ (row & 7);
        bfr[nt][kk] = *(const s16x8*)(Bl + row * 64 + s * 8);
      }
    }
    #pragma unroll
    for (int mt = 0; mt < 4; ++mt)
      #pragma unroll
      for (int nt = 0; nt < 4; ++nt) {
        acc[mt][nt] = __builtin_amdgcn_mfma_f32_16x16x32_bf16(
            af[mt][0], bfr[nt][0], acc[mt][nt], 0, 0, 0);
        acc[mt][nt] = __builtin_amdgcn_mfma_f32_16x16x32_bf16(
            af[mt][1], bfr[nt][1], acc[mt][nt], 0, 0, 0);
      }
    __syncthreads();
  }

  #pragma unroll
  for (int nt = 0; nt < 4; ++nt) {
    int n = n0 + nh * 64 + nt * 16 + l15;
    float bb = bias[n];
    int seg = n >> 8;
    int ncol = n & 255;
    #pragma unroll
    for (int mt = 0; mt < 4; ++mt) {
      int m = m0 + mh * 64 + mt * 16 + quad * 4;
      f32x4 a = acc[mt][nt];
      #pragma unroll
      for (int r = 0; r < 4; ++r) {
        float val = a[r] + bb;
        size_t idx = (size_t)(m + r) * 256 + ncol;
        if (seg == 0) hout[idx] = f2bf(val);
        else if (seg == 1) vq[idx] = f2e4m3(val);
        else if (seg == 2) Qaq[idx] = f2e4m3(val);
        else Kaq[idx] = f2e4m3(val);
      }
    }
  }
}

// ---------------------------------------------------------------------------
// K4 edge scores, CSR order, 64 edges/WG, fp8 Qa/Ka gathers.  19.5 KB LDS,
// 8 WGs/CU.  Head partials summed cross-wave via LDS atomics into pl[64][8].
// Per-WG Z partial PLAIN-stored to Zblk[wg] (no global atomics anywhere).
// ---------------------------------------------------------------------------
__global__ __launch_bounds__(256, 8) void edge_scores_kernel(
    const int* __restrict__ perm, const int2* __restrict__ st2,
    const float* __restrict__ ef,
    const uint8_t* __restrict__ Qaq, const uint8_t* __restrict__ Kaq,
    const unsigned short* __restrict__ WeaT, const float* __restrict__ bcomb,
    const float* __restrict__ A2p, const float* __restrict__ a2g,
    float* __restrict__ Pp, float* __restrict__ Zblk)
{
  __shared__ __align__(16) unsigned short efl[64 * 64];  // 8 KB
  __shared__ __align__(16) float A2l[8][256];            // 8 KB
  __shared__ __align__(16) float pl[64][8];              // 2 KB
  __shared__ __align__(16) float bcl[256];               // 1 KB
  __shared__ __align__(8) int stl[2][64];                // 0.5 KB
  const int t = threadIdx.x;
  const int wid = t >> 6, lane = t & 63, quad = lane >> 4, l15 = lane & 15;
  // XCD-chunked swizzle: 4096 WGs -> each XCD gets a contiguous 512-WG chunk
  const int wg = ((blockIdx.x & 7) << 9) | (blockIdx.x >> 3);
  const int eb = wg * 64;
  const int r = t >> 2, q4 = t & 3;

  {  // A2l head-major
    const f32x4 x0 = *(const f32x4*)(A2p + t * 8);
    const f32x4 x1 = *(const f32x4*)(A2p + t * 8 + 4);
    A2l[0][t] = x0[0]; A2l[1][t] = x0[1]; A2l[2][t] = x0[2]; A2l[3][t] = x0[3];
    A2l[4][t] = x1[0]; A2l[5][t] = x1[1]; A2l[6][t] = x1[2]; A2l[7][t] = x1[3];
  }
  if (t < 64) {
    int64_t sv = __builtin_nontemporal_load(
        (const int64_t*)st2 + (eb + t));
    stl[0][t] = (int)(sv & 0xFFFFFFFFll);
    stl[1][t] = (int)(sv >> 32);
  } else if (t < 128) {
    ((f32x4*)bcl)[t - 64] = ((const f32x4*)bcomb)[t - 64];
  } else if (t < 192) {  // zero pl
    ((f32x4*)pl)[(t - 128) * 2] = (f32x4){0.f, 0.f, 0.f, 0.f};
    ((f32x4*)pl)[(t - 128) * 2 + 1] = (f32x4){0.f, 0.f, 0.f, 0.f};
  }
  {  // ef rows (gathered via perm), nt-loads, bf16 convert, swizzled LDS
    int pe = __builtin_nontemporal_load(&perm[eb + r]);
    const f32x4* sp = (const f32x4*)(ef + (size_t)pe * 64 + q4 * 16);
    f32x4 v0 = __builtin_nontemporal_load(sp);
    f32x4 v1 = __builtin_nontemporal_load(sp + 1);
    f32x4 v2 = __builtin_nontemporal_load(sp + 2);
    f32x4 v3 = __builtin_nontemporal_load(sp + 3);
    u16x8 w0 = { f2bf(v0[0]), f2bf(v0[1]), f2bf(v0[2]), f2bf(v0[3]),
                 f2bf(v1[0]), f2bf(v1[1]), f2bf(v1[2]), f2bf(v1[3]) };
    u16x8 w1 = { f2bf(v2[0]), f2bf(v2[1]), f2bf(v2[2]), f2bf(v2[3]),
                 f2bf(v3[0]), f2bf(v3[1]), f2bf(v3[2]), f2bf(v3[3]) };
    int s0_ = (2 * q4) ^ (r & 7), s1_ = (2 * q4 + 1) ^ (r & 7);
    *(u16x8*)&efl[r * 64 + s0_ * 8] = w0;
    *(u16x8*)&efl[r * 64 + s1_ * 8] = w1;
  }
  // WeaT A-fragments in registers
  s16x8 af0[4], af1[4];
  #pragma unroll
  for (int ct = 0; ct < 4; ++ct) {
    int ch = wid * 64 + ct * 16 + l15;
    af0[ct] = *(const s16x8*)(WeaT + ch * 64 + quad * 8);
    af1[ct] = *(const s16x8*)(WeaT + ch * 64 + 32 + quad * 8);
  }
  __syncthreads();

  // fp8 gathers initialize acc
  f32x4 acc[4][4];  // [ct][et]
  {
    const int cb = wid * 64 + quad * 16;
    uint4 qv[4], kv[4];
    #pragma unroll
    for (int x = 0; x < 4; ++x) {
      int e = x * 16 + l15;
      qv[x] = *(const uint4*)(Qaq + (size_t)stl[0][e] * 256 + cb);
      kv[x] = *(const uint4*)(Kaq + (size_t)stl[1][e] * 256 + cb);
    }
    #pragma unroll
    for (int x = 0; x < 4; ++x) {
      float qf[16], kf[16];
      dec16(qv[x], qf); dec16(kv[x], kf);
      #pragma unroll
      for (int ct = 0; ct < 4; ++ct)
        #pragma unroll
        for (int rr = 0; rr < 4; ++rr)
          acc[ct][x][rr] = qf[ct * 4 + rr] + kf[ct * 4 + rr];
    }
  }

  // MFMA: Ea accumulates on top
  #pragma unroll
  for (int et = 0; et < 4; ++et) {
    int e = et * 16 + l15;
    s16x8 b0 = *(const s16x8*)(efl + e * 64 + ((quad ^ (e & 7)) * 8));
    s16x8 b1 = *(const s16x8*)(efl + e * 64 + (((4 + quad) ^ (e & 7)) * 8));
    #pragma unroll
    for (int ct = 0; ct < 4; ++ct) {
      acc[ct][et] = __builtin_amdgcn_mfma_f32_16x16x32_bf16(af0[ct], b0, acc[ct][et], 0, 0, 0);
      acc[ct][et] = __builtin_amdgcn_mfma_f32_16x16x32_bf16(af1[ct], b1, acc[ct][et], 0, 0, 0);
    }
  }

  // epilogue: lrelu + partials of mid@A2 (head-major A2l)
  float part[4][8];
  #pragma unroll
  for (int i = 0; i < 4; ++i)
    #pragma unroll
    for (int j = 0; j < 8; ++j) part[i][j] = 0.f;
  #pragma unroll
  for (int ct = 0; ct < 4; ++ct) {
    int chb = wid * 64 + ct * 16 + quad * 4;
    f32x4 bc = *(const f32x4*)&bcl[chb];
    float mv[4][4];
    #pragma unroll
    for (int et = 0; et < 4; ++et)
      #pragma unroll
      for (int rr = 0; rr < 4; ++rr)
        mv[et][rr] = lrelu(acc[ct][et][rr] + bc[rr]);
    #pragma unroll
    for (int hh = 0; hh < 8; ++hh) {
      f32x4 w = *(const f32x4*)&A2l[hh][chb];
      #pragma unroll
      for (int et = 0; et < 4; ++et)
        part[et][hh] += mv[et][0] * w[0] + mv[et][1] * w[1] +
                        mv[et][2] * w[2] + mv[et][3] * w[3];
    }
  }
  // reduce across quads in-wave, then cross-wave via LDS atomics
  #pragma unroll
  for (int et = 0; et < 4; ++et)
    #pragma unroll
    for (int hh = 0; hh < 8; ++hh) {
      part[et][hh] += __shfl_xor(part[et][hh], 16);
      part[et][hh] += __shfl_xor(part[et][hh], 32);
    }
  if (quad == 0) {
    #pragma unroll
    for (int et = 0; et < 4; ++et) {
      int e = et * 16 + l15;
      #pragma unroll
      for (int hh = 0; hh < 8; ++hh)
        atomicAdd(&pl[e][hh], part[et][hh]);
    }
  }
  __syncthreads();
  if (t < 64) {
    f32x4 t0 = *(const f32x4*)&pl[t][0];
    f32x4 t1 = *(const f32x4*)&pl[t][4];
    const f32x4 a20 = *(const f32x4*)a2g;
    const f32x4 a21 = *(const f32x4*)(a2g + 4);
    float sacc = 0.f;
    #pragma unroll
    for (int j = 0; j < 4; ++j) {
      sacc += lrelu(t0[j] + a20[j]);
      sacc += lrelu(t1[j] + a21[j]);
    }
    float p = __expf(sacc * 0.125f);
    __builtin_nontemporal_store(p, &Pp[eb + t]);
    #pragma unroll
    for (int d = 1; d < 64; d <<= 1) p += __shfl_xor(p, d);
    if (t == 0) Zblk[wg] = p;   // plain store — no atomics
  }
}

// ---------------------------------------------------------------------------
// K5 per-node accumulate + residual + LayerNorm; reduces Zblk[4096] per WG
// (L2-broadcast), fp8 v gathers, 4 nodes/WG.
// ---------------------------------------------------------------------------
__global__ __launch_bounds__(256) void scatter_ln_kernel(
    const int* __restrict__ startA, const float* __restrict__ Pp,
    const float* __restrict__ Zblk, const int2* __restrict__ st2,
    const uint8_t* __restrict__ vq, const unsigned short* __restrict__ hbuf,
    const float* __restrict__ gamma, const float* __restrict__ beta,
    float* __restrict__ out)
{
  __shared__ float zsl[4];
  const int t = threadIdx.x;
  const int wid = t >> 6, lane = t & 63;
  const int n = blockIdx.x * 4 + wid;
  // reduce Zblk[4096]
  float zp = 0.f;
  {
    const f32x4* zb = (const f32x4*)Zblk;
    #pragma unroll
    for (int i = 0; i < 4; ++i) {
      f32x4 v = zb[t * 4 + i];
      zp += v[0] + v[1] + v[2] + v[3];
    }
  }
  #pragma unroll
  for (int d = 1; d < 64; d <<= 1) zp += __shfl_xor(zp, d);
  if (lane == 0) zsl[wid] = zp;
  __syncthreads();
  const float invZ = 1.f / (zsl[0] + zsl[1] + zsl[2] + zsl[3]);

  const int s0 = startA[n], s1 = startA[n + 1];
  float a0 = 0.f, a1_ = 0.f, a2_ = 0.f, a3_ = 0.f;
  int i = s0;
  for (; i + 3 < s1; i += 4) {
    float w0 = Pp[i], w1 = Pp[i + 1], w2 = Pp[i + 2], w3 = Pp[i + 3];
    int t0 = st2[i].y, t1 = st2[i + 1].y, t2 = st2[i + 2].y, t3 = st2[i + 3].y;
    uint32_t e0 = *(const uint32_t*)(vq + (size_t)t0 * 256 + lane * 4);
    uint32_t e1 = *(const uint32_t*)(vq + (size_t)t1 * 256 + lane * 4);
    uint32_t e2 = *(const uint32_t*)(vq + (size_t)t2 * 256 + lane * 4);
    uint32_t e3 = *(const uint32_t*)(vq + (size_t)t3 * 256 + lane * 4);
    float f0[4], f1[4], f2[4], f3[4];
    dec4(e0, f0); dec4(e1, f1); dec4(e2, f2); dec4(e3, f3);
    a0 += w0 * f0[0] + w1 * f1[0] + w2 * f2[0] + w3 * f3[0];
    a1_ += w0 * f0[1] + w1 * f1[1] + w2 * f2[1] + w3 * f3[1];
    a2_ += w0 * f0[2] + w1 * f1[2] + w2 * f2[2] + w3 * f3[2];
    a3_ += w0 * f0[3] + w1 * f1[3] + w2 * f2[3] + w3 * f3[3];
  }
  for (; i < s1; ++i) {
    float w0 = Pp[i];
    uint32_t e0 = *(const uint32_t*)(vq + (size_t)st2[i].y * 256 + lane * 4);
    float f0[4];
    dec4(e0, f0);
    a0 += w0 * f0[0]; a1_ += w0 * f0[1]; a2_ += w0 * f0[2]; a3_ += w0 * f0[3];
  }
  a0 *= invZ; a1_ *= invZ; a2_ *= invZ; a3_ *= invZ;
  u16x4 hv = __builtin_nontemporal_load(
      (const u16x4*)(hbuf + (size_t)n * 256 + lane * 4));
  float x0 = bf2f(hv[0]) + a0, x1 = bf2f(hv[1]) + a1_;
  float x2 = bf2f(hv[2]) + a2_, x3 = bf2f(hv[3]) + a3_;
  float sum = x0 + x1 + x2 + x3;
  float sq = x0 * x0 + x1 * x1 + x2 * x2 + x3 * x3;
  #pragma unroll
  for (int d = 1; d < 64; d <<= 1) { sum += __shfl_xor(sum, d); sq += __shfl_xor(sq, d); }
  float mu = sum * (1.f / 256.f);
  float var = sq * (1.f / 256.f) - mu * mu;
  float rstd = rsqrtf(var + 1e-5f);
  f32x4 g = *(const f32x4*)(gamma + lane * 4);
  f32x4 b = *(const f32x4*)(beta + lane * 4);
  f32x4 o;
  o[0] = (x0 - mu) * rstd * g[0] + b[0];
  o[1] = (x1 - mu) * rstd * g[1] + b[1];
  o[2] = (x2 - mu) * rstd * g[2] + b[2];
  o[3] = (x3 - mu) * rstd * g[3] + b[3];
  *(f32x4*)(out + (size_t)n * 256 + lane * 4) = o;
}

extern "C" void kernel_launch(void* const* d_in, const int* in_sizes, int n_in,
                              void* d_out, int out_size, void* d_ws, size_t ws_size,
                              hipStream_t stream)
{
  (void)in_sizes; (void)n_in; (void)out_size; (void)ws_size;
  const float* nf    = (const float*)d_in[0];
  const int*   eidx  = (const int*)  d_in[1];
  const float* ef    = (const float*)d_in[2];
  const float* Wn    = (const float*)d_in[3];
  const float* bn    = (const float*)d_in[4];
  const float* Wq    = (const float*)d_in[5];
  const float* bq    = (const float*)d_in[6];
  const float* Wk    = (const float*)d_in[7];
  const float* bk    = (const float*)d_in[8];
  const float* Wv    = (const float*)d_in[9];
  const float* bv    = (const float*)d_in[10];
  const float* We    = (const float*)d_in[11];
  const float* be    = (const float*)d_in[12];
  const float* A1    = (const float*)d_in[13];
  const float* a1    = (const float*)d_in[14];
  const float* A2    = (const float*)d_in[15];
  const float* a2    = (const float*)d_in[16];
  const float* gamma = (const float*)d_in[17];
  const float* beta  = (const float*)d_in[18];
  float* out = (float*)d_out;

  char* ws = (char*)d_ws;
  size_t off = 0;
  auto take = [&](size_t bytes) {
    size_t r = off; off += (bytes + 255) & ~(size_t)255; return r;
  };
  int*   deg     = (int*)  (ws + take((size_t)NN * 4));   // memset below
  int*   startA  = (int*)  (ws + take((size_t)(NN + 1) * 4));
  int*   cursor  = (int*)  (ws + take((size_t)NN * 4));
  int*   perm    = (int*)  (ws + take((size_t)EE * 4));
  int2*  st2     = (int2*) (ws + take((size_t)EE * 8));
  float* Pp      = (float*)(ws + take((size_t)EE * 4));
  float* Zblk    = (float*)(ws + take(4096 * 4));
  unsigned short* hbuf = (unsigned short*)(ws + take((size_t)NN * DD * 2));
  uint8_t* vqB   = (uint8_t*)(ws + take((size_t)NN * DD));
  uint8_t* QaB   = (uint8_t*)(ws + take((size_t)NN * DD));
  uint8_t* KaB   = (uint8_t*)(ws + take((size_t)NN * DD));
  unsigned short* BcatT = (unsigned short*)(ws + take((size_t)1024 * 256 * 2));
  float* bcat    = (float*)(ws + take(1024 * 4));
  unsigned short* WeaT  = (unsigned short*)(ws + take((size_t)256 * 64 * 2));
  float* bcomb   = (float*)(ws + take(256 * 4));
  float* A2p     = (float*)(ws + take(256 * 8 * 4));
  unsigned short* nfb   = (unsigned short*)(ws + take((size_t)NN * DD * 2));

  // zero deg (at ws start)
  (void)hipMemsetAsync(d_ws, 0, (size_t)NN * 4, stream);

  prep_hist_kernel<<<1731, 256, 0, stream>>>(Wn, bn, Wq, bq, Wk, bk, Wv, bv,
                                             We, be, A1, a1, A2, eidx,
                                             BcatT, bcat, WeaT, bcomb, A2p, deg);
  conv_scan_kernel<<<2049, 256, 0, stream>>>(nf, nfb, deg, startA, cursor);
  gemm_perm_kernel<<<2048, 256, 0, stream>>>(nfb, BcatT, bcat, hbuf, vqB,
                                             QaB, KaB, eidx, cursor,
                                             perm, st2);
  edge_scores_kernel<<<4096, 256, 0, stream>>>(perm, st2, ef, QaB, KaB,
                                               WeaT, bcomb, A2p, a2, Pp, Zblk);
  scatter_ln_kernel<<<NN / 4, 256, 0, stream>>>(startA, Pp, Zblk, st2,
                                                vqB, hbuf, gamma, beta, out);
}

// Round 7
// 318.730 us; speedup vs baseline: 1.5847x; 1.5847x over previous
//
#include <hip/hip_runtime.h>
#include <stdint.h>

#define NN 16384
#define EE 262144
#define DD 256

typedef float f32x4 __attribute__((ext_vector_type(4)));
typedef float f32x2 __attribute__((ext_vector_type(2)));
typedef short s16x8 __attribute__((ext_vector_type(8)));
typedef unsigned short u16x4 __attribute__((ext_vector_type(4)));
typedef unsigned short u16x8 __attribute__((ext_vector_type(8)));

#define AS1 __attribute__((address_space(1)))
#define AS3 __attribute__((address_space(3)))

__device__ __forceinline__ float bf2f(unsigned short u) {
  union { unsigned int i; float f; } v; v.i = ((unsigned int)u) << 16; return v.f;
}
__device__ __forceinline__ unsigned short f2bf(float f) {
  union { float f; unsigned int i; } v; v.f = f;
  unsigned int r = v.i + 0x7fffu + ((v.i >> 16) & 1u);
  return (unsigned short)(r >> 16);
}
__device__ __forceinline__ float lrelu(float x) { return x > 0.f ? x : 0.2f * x; }

// ---- OCP e4m3fn helpers (subnormals flushed; |x|>=448 clamps to 448) ----
__device__ __forceinline__ uint8_t f2e4m3(float x) {
  uint32_t xu = __float_as_uint(x);
  uint32_t s = (xu >> 24) & 0x80u;
  float a = fabsf(x);
  if (a >= 448.f) return (uint8_t)(s | 0x7Eu);
  if (a < 0.015625f) return (uint8_t)s;
  uint32_t u = xu & 0x7FFFFFFFu;
  u = u + 0x0007FFFFu + ((u >> 20) & 1u);   // RNE to 3-bit mantissa
  uint32_t E = (u >> 23) - 120u;            // exp-127+7
  if (E >= 16u) return (uint8_t)(s | 0x7Eu);
  return (uint8_t)(s | (E << 3) | ((u >> 20) & 7u));
}
__device__ __forceinline__ float e4m3f(uint32_t b) {
  uint32_t ex = b & 0x78u;
  uint32_t bits = ((b & 0x80u) << 24) | (((b & 0x7fu) << 20) + (120u << 23));
  union { uint32_t u; float f; } v;
  v.u = ex ? bits : ((b & 0x80u) << 24);
  return v.f;
}
#if defined(__has_builtin)
#if __has_builtin(__builtin_amdgcn_cvt_pk_f32_fp8)
#define HAVE_CVT_FP8 1
#endif
#endif
__device__ __forceinline__ void dec4(uint32_t w, float* f) {
#ifdef HAVE_CVT_FP8
  f32x2 lo = __builtin_amdgcn_cvt_pk_f32_fp8(w, false);
  f32x2 hi = __builtin_amdgcn_cvt_pk_f32_fp8(w, true);
  f[0] = lo[0]; f[1] = lo[1]; f[2] = hi[0]; f[3] = hi[1];
#else
  f[0] = e4m3f(w & 0xFFu); f[1] = e4m3f((w >> 8) & 0xFFu);
  f[2] = e4m3f((w >> 16) & 0xFFu); f[3] = e4m3f(w >> 24);
#endif
}
__device__ __forceinline__ void dec16(uint4 v, float* f) {
  dec4(v.x, f); dec4(v.y, f + 4); dec4(v.z, f + 8); dec4(v.w, f + 12);
}

// channel-storage permutation (involution): swap ct<->quad fields so each
// lane's 16 MFMA accumulator channels are 16 CONTIGUOUS Qa/Ka columns.
__device__ __forceinline__ int chanperm(int c) {
  int hi = c & ~63, loc = c & 63;
  int ct = loc >> 4, quad = (loc >> 2) & 3, rr = loc & 3;
  return hi | (quad * 16 + ct * 4 + rr);
}

// ---------------------------------------------------------------------------
// K1 = prep (weight algebra, blocks 0..706) + src-degree hist (707..1730).
// ---------------------------------------------------------------------------
__global__ __launch_bounds__(256) void prep_hist_kernel(
    const float* __restrict__ Wn, const float* __restrict__ bn,
    const float* __restrict__ Wq, const float* __restrict__ bq,
    const float* __restrict__ Wk, const float* __restrict__ bk,
    const float* __restrict__ Wv, const float* __restrict__ bv,
    const float* __restrict__ We, const float* __restrict__ be,
    const float* __restrict__ A1, const float* __restrict__ a1,
    const float* __restrict__ A2, const int* __restrict__ eidx,
    unsigned short* __restrict__ BcatT, float* __restrict__ bcat,
    unsigned short* __restrict__ WeaT, float* __restrict__ bcomb,
    float* __restrict__ A2p, int* __restrict__ deg)
{
  const int b = blockIdx.x, t = threadIdx.x;
  if (b < 256) {                 // Wqa
    float acc = 0.f;
    for (int j = 0; j < 256; ++j) acc += Wq[b * 256 + j] * A1[j * 256 + t];
    BcatT[(512 + t) * 256 + b] = f2bf(acc);
  } else if (b < 512) {          // Wka
    int k = b - 256; float acc = 0.f;
    for (int j = 0; j < 256; ++j) acc += Wk[k * 256 + j] * A1[(256 + j) * 256 + t];
    BcatT[(768 + t) * 256 + k] = f2bf(acc);
  } else if (b < 576) {          // WeaT row chanperm(t), col k = b-512
    int k = b - 512; float acc = 0.f;
    for (int j = 0; j < 256; ++j) acc += We[k * 256 + j] * A1[(512 + j) * 256 + t];
    WeaT[chanperm(t) * 64 + k] = f2bf(acc);
  } else if (b == 576) {         // bcomb (storage order)
    float acc = a1[t];
    for (int j = 0; j < 256; ++j) {
      acc += bq[j] * A1[j * 256 + t];
      acc += bk[j] * A1[(256 + j) * 256 + t];
      acc += be[j] * A1[(512 + j) * 256 + t];
    }
    bcomb[chanperm(t)] = acc;
  } else if (b < 705) {          // transpose Wn, Wv into BcatT rows 0..511
    int b2 = b - 577;
    for (int rr = 0; rr < 4; ++rr) {
      int np = b2 * 4 + rr;
      float v = (np < 256) ? Wn[t * 256 + np] : Wv[t * 256 + (np - 256)];
      BcatT[np * 256 + t] = f2bf(v);
    }
  } else if (b == 705) {         // bcat
    bcat[t] = bn[t];
    bcat[256 + t] = bv[t];
    bcat[512 + t] = 0.f;
    bcat[768 + t] = 0.f;
  } else if (b == 706) {         // A2p (storage order)
    int m = chanperm(t);
    for (int j = 0; j < 8; ++j) A2p[m * 8 + j] = A2[t * 8 + j];
  } else {                       // hist
    int e = (b - 707) * 256 + t;
    atomicAdd(&deg[eidx[e]], 1);
  }
}

// ---------------------------------------------------------------------------
// K2 = nf f32->bf16 conversion (blocks 0..2047) + CSR scan (block 2048).
// ---------------------------------------------------------------------------
__global__ __launch_bounds__(256) void conv_scan_kernel(
    const float* __restrict__ in, unsigned short* __restrict__ o,
    const int* __restrict__ deg, int* __restrict__ startA,
    int* __restrict__ cursor)
{
  const int t = threadIdx.x;
  if (blockIdx.x < 2048) {
    size_t i = (size_t)blockIdx.x * 256 + t;
    const f32x4* p = (const f32x4*)(in + i * 8);
    f32x4 a = p[0], b = p[1];
    u16x8 r = { f2bf(a[0]), f2bf(a[1]), f2bf(a[2]), f2bf(a[3]),
                f2bf(b[0]), f2bf(b[1]), f2bf(b[2]), f2bf(b[3]) };
    *(u16x8*)(o + i * 8) = r;
    return;
  }
  __shared__ int ls[256];
  int4 d[16];
  int s = 0;
  #pragma unroll
  for (int i = 0; i < 16; ++i) {
    d[i] = ((const int4*)deg)[t * 16 + i];
    s += d[i].x + d[i].y + d[i].z + d[i].w;
  }
  ls[t] = s;
  __syncthreads();
  for (int dd = 1; dd < 256; dd <<= 1) {
    int v = ls[t];
    if (t >= dd) v += ls[t - dd];
    __syncthreads();
    ls[t] = v;
    __syncthreads();
  }
  int run = ls[t] - s;
  #pragma unroll
  for (int i = 0; i < 16; ++i) {
    int4 ov;
    ov.x = run; run += d[i].x;
    ov.y = run; run += d[i].y;
    ov.z = run; run += d[i].z;
    ov.w = run; run += d[i].w;
    ((int4*)startA)[t * 16 + i] = ov;
    ((int4*)cursor)[t * 16 + i] = ov;
  }
  if (t == 255) startA[NN] = run;
}

// ---------------------------------------------------------------------------
// K3 = perm scatter (blocks 0..1023) + node GEMM (1024..2047).
// GEMM out: h bf16, v/Qa/Ka fp8 e4m3.  perm writes st2 = (src,tgt) pairs.
// ---------------------------------------------------------------------------
__global__ __launch_bounds__(256, 1) void gemm_perm_kernel(
    const unsigned short* __restrict__ Abf,
    const unsigned short* __restrict__ BT,
    const float* __restrict__ bias,
    unsigned short* __restrict__ hout, uint8_t* __restrict__ vq,
    uint8_t* __restrict__ Qaq, uint8_t* __restrict__ Kaq,
    const int* __restrict__ eidx, int* __restrict__ cursor,
    int* __restrict__ perm, int2* __restrict__ st2)
{
  const int t = threadIdx.x;
  if (blockIdx.x < 1024) {       // perm part
    int e = blockIdx.x * 256 + t;
    int s = eidx[e], tg = eidx[EE + e];
    int pos = atomicAdd(&cursor[s], 1);
    perm[pos] = e;
    st2[pos] = make_int2(s, tg);
    return;
  }
  __shared__ __align__(16) unsigned short Al[128 * 64];
  __shared__ __align__(16) unsigned short Bl[128 * 64];
  const int b2 = blockIdx.x - 1024;
  const int wid = t >> 6, lane = t & 63;
  const int quad = lane >> 4, l15 = lane & 15;
  const int mblk = b2 & 127, nblk = b2 >> 7;
  const int m0 = mblk * 128, n0 = nblk * 128;
  const int mh = wid >> 1, nh = wid & 1;
  const int srow = lane >> 3, sslot = lane & 7;

  f32x4 acc[4][4];
  #pragma unroll
  for (int i = 0; i < 4; ++i)
    #pragma unroll
    for (int j = 0; j < 4; ++j) acc[i][j] = (f32x4){0.f, 0.f, 0.f, 0.f};

  for (int ks = 0; ks < 4; ++ks) {
    const int k0 = ks * 64;
    #pragma unroll
    for (int j = 0; j < 4; ++j) {
      int cj = wid * 4 + j;
      int row = cj * 8 + srow;
      const unsigned short* ga =
          Abf + (size_t)(m0 + row) * 256 + k0 + ((sslot ^ (row & 7)) * 8);
      __builtin_amdgcn_global_load_lds((AS1 const void*)ga,
                                       (AS3 void*)(Al + cj * 512), 16, 0, 0);
      const unsigned short* gb =
          BT + (size_t)(n0 + row) * 256 + k0 + ((sslot ^ (row & 7)) * 8);
      __builtin_amdgcn_global_load_lds((AS1 const void*)gb,
                                       (AS3 void*)(Bl + cj * 512), 16, 0, 0);
    }
    __syncthreads();
    s16x8 af[4][2], bfr[4][2];
    #pragma unroll
    for (int mt = 0; mt < 4; ++mt) {
      int row = mh * 64 + mt * 16 + l15;
      #pragma unroll
      for (int kk = 0; kk < 2; ++kk) {
        int s = (kk * 4 + quad) ^ (row & 7);
        af[mt][kk] = *(const s16x8*)(Al + row * 64 + s * 8);
      }
    }
    #pragma unroll
    for (int nt = 0; nt < 4; ++nt) {
      int row = nh * 64 + nt * 16 + l15;
      #pragma unroll
      for (int kk = 0; kk < 2; ++kk) {
        int s = (kk * 4 + quad) ^ (row & 7);
        bfr[nt][kk] = *(const s16x8*)(Bl + row * 64 + s * 8);
      }
    }
    #pragma unroll
    for (int mt = 0; mt < 4; ++mt)
      #pragma unroll
      for (int nt = 0; nt < 4; ++nt) {
        acc[mt][nt] = __builtin_amdgcn_mfma_f32_16x16x32_bf16(
            af[mt][0], bfr[nt][0], acc[mt][nt], 0, 0, 0);
        acc[mt][nt] = __builtin_amdgcn_mfma_f32_16x16x32_bf16(
            af[mt][1], bfr[nt][1], acc[mt][nt], 0, 0, 0);
      }
    __syncthreads();
  }

  #pragma unroll
  for (int nt = 0; nt < 4; ++nt) {
    int n = n0 + nh * 64 + nt * 16 + l15;
    float bb = bias[n];
    int seg = n >> 8;
    int ncol = n & 255;
    #pragma unroll
    for (int mt = 0; mt < 4; ++mt) {
      int m = m0 + mh * 64 + mt * 16 + quad * 4;
      f32x4 a = acc[mt][nt];
      #pragma unroll
      for (int r = 0; r < 4; ++r) {
        float val = a[r] + bb;
        size_t idx = (size_t)(m + r) * 256 + ncol;
        if (seg == 0) hout[idx] = f2bf(val);
        else if (seg == 1) vq[idx] = f2e4m3(val);
        else if (seg == 2) Qaq[idx] = f2e4m3(val);
        else Kaq[idx] = f2e4m3(val);
      }
    }
  }
}

// ---------------------------------------------------------------------------
// K4 edge scores, CSR order, 64 edges/WG, fp8 Qa/Ka gathers.  19.9 KB LDS.
// __launch_bounds__(256,2): unified VGPR+AGPR cap 256 -> ZERO spills (the
// r2-r6 WRITE_SIZE was scratch spill traffic from over-tight caps).
// ---------------------------------------------------------------------------
__global__ __launch_bounds__(256, 2) void edge_scores_kernel(
    const int* __restrict__ perm, const int2* __restrict__ st2,
    const float* __restrict__ ef,
    const uint8_t* __restrict__ Qaq, const uint8_t* __restrict__ Kaq,
    const unsigned short* __restrict__ WeaT, const float* __restrict__ bcomb,
    const float* __restrict__ A2p, const float* __restrict__ a2g,
    float* __restrict__ Pp, float* __restrict__ Zblk)
{
  __shared__ __align__(16) unsigned short efl[64 * 64];  // 8 KB
  __shared__ __align__(16) float A2l[8][256];            // 8 KB
  __shared__ __align__(16) float pl[64][8];              // 2 KB
  __shared__ __align__(16) float bcl[256];               // 1 KB
  __shared__ __align__(8) int stl[2][64];                // 0.5 KB
  const int t = threadIdx.x;
  const int wid = t >> 6, lane = t & 63, quad = lane >> 4, l15 = lane & 15;
  // XCD-chunked swizzle: 4096 WGs -> each XCD gets a contiguous 512-WG chunk
  const int wg = ((blockIdx.x & 7) << 9) | (blockIdx.x >> 3);
  const int eb = wg * 64;
  const int r = t >> 2, q4 = t & 3;

  {  // A2l head-major
    const f32x4 x0 = *(const f32x4*)(A2p + t * 8);
    const f32x4 x1 = *(const f32x4*)(A2p + t * 8 + 4);
    A2l[0][t] = x0[0]; A2l[1][t] = x0[1]; A2l[2][t] = x0[2]; A2l[3][t] = x0[3];
    A2l[4][t] = x1[0]; A2l[5][t] = x1[1]; A2l[6][t] = x1[2]; A2l[7][t] = x1[3];
  }
  if (t < 64) {
    int64_t sv = __builtin_nontemporal_load(
        (const int64_t*)st2 + (eb + t));
    stl[0][t] = (int)(sv & 0xFFFFFFFFll);
    stl[1][t] = (int)(sv >> 32);
  } else if (t < 128) {
    ((f32x4*)bcl)[t - 64] = ((const f32x4*)bcomb)[t - 64];
  } else if (t < 192) {  // zero pl
    ((f32x4*)pl)[(t - 128) * 2] = (f32x4){0.f, 0.f, 0.f, 0.f};
    ((f32x4*)pl)[(t - 128) * 2 + 1] = (f32x4){0.f, 0.f, 0.f, 0.f};
  }
  {  // ef rows (gathered via perm), nt-loads, bf16 convert, swizzled LDS
    int pe = __builtin_nontemporal_load(&perm[eb + r]);
    const f32x4* sp = (const f32x4*)(ef + (size_t)pe * 64 + q4 * 16);
    f32x4 v0 = __builtin_nontemporal_load(sp);
    f32x4 v1 = __builtin_nontemporal_load(sp + 1);
    f32x4 v2 = __builtin_nontemporal_load(sp + 2);
    f32x4 v3 = __builtin_nontemporal_load(sp + 3);
    u16x8 w0 = { f2bf(v0[0]), f2bf(v0[1]), f2bf(v0[2]), f2bf(v0[3]),
                 f2bf(v1[0]), f2bf(v1[1]), f2bf(v1[2]), f2bf(v1[3]) };
    u16x8 w1 = { f2bf(v2[0]), f2bf(v2[1]), f2bf(v2[2]), f2bf(v2[3]),
                 f2bf(v3[0]), f2bf(v3[1]), f2bf(v3[2]), f2bf(v3[3]) };
    int s0_ = (2 * q4) ^ (r & 7), s1_ = (2 * q4 + 1) ^ (r & 7);
    *(u16x8*)&efl[r * 64 + s0_ * 8] = w0;
    *(u16x8*)&efl[r * 64 + s1_ * 8] = w1;
  }
  // WeaT A-fragments in registers
  s16x8 af0[4], af1[4];
  #pragma unroll
  for (int ct = 0; ct < 4; ++ct) {
    int ch = wid * 64 + ct * 16 + l15;
    af0[ct] = *(const s16x8*)(WeaT + ch * 64 + quad * 8);
    af1[ct] = *(const s16x8*)(WeaT + ch * 64 + 32 + quad * 8);
  }
  __syncthreads();

  // fp8 gathers initialize acc
  f32x4 acc[4][4];  // [ct][et]
  {
    const int cb = wid * 64 + quad * 16;
    uint4 qv[4], kv[4];
    #pragma unroll
    for (int x = 0; x < 4; ++x) {
      int e = x * 16 + l15;
      qv[x] = *(const uint4*)(Qaq + (size_t)stl[0][e] * 256 + cb);
      kv[x] = *(const uint4*)(Kaq + (size_t)stl[1][e] * 256 + cb);
    }
    #pragma unroll
    for (int x = 0; x < 4; ++x) {
      float qf[16], kf[16];
      dec16(qv[x], qf); dec16(kv[x], kf);
      #pragma unroll
      for (int ct = 0; ct < 4; ++ct)
        #pragma unroll
        for (int rr = 0; rr < 4; ++rr)
          acc[ct][x][rr] = qf[ct * 4 + rr] + kf[ct * 4 + rr];
    }
  }

  // MFMA: Ea accumulates on top
  #pragma unroll
  for (int et = 0; et < 4; ++et) {
    int e = et * 16 + l15;
    s16x8 b0 = *(const s16x8*)(efl + e * 64 + ((quad ^ (e & 7)) * 8));
    s16x8 b1 = *(const s16x8*)(efl + e * 64 + (((4 + quad) ^ (e & 7)) * 8));
    #pragma unroll
    for (int ct = 0; ct < 4; ++ct) {
      acc[ct][et] = __builtin_amdgcn_mfma_f32_16x16x32_bf16(af0[ct], b0, acc[ct][et], 0, 0, 0);
      acc[ct][et] = __builtin_amdgcn_mfma_f32_16x16x32_bf16(af1[ct], b1, acc[ct][et], 0, 0, 0);
    }
  }

  // epilogue: lrelu + partials of mid@A2 (head-major A2l)
  float part[4][8];
  #pragma unroll
  for (int i = 0; i < 4; ++i)
    #pragma unroll
    for (int j = 0; j < 8; ++j) part[i][j] = 0.f;
  #pragma unroll
  for (int ct = 0; ct < 4; ++ct) {
    int chb = wid * 64 + ct * 16 + quad * 4;
    f32x4 bc = *(const f32x4*)&bcl[chb];
    float mv[4][4];
    #pragma unroll
    for (int et = 0; et < 4; ++et)
      #pragma unroll
      for (int rr = 0; rr < 4; ++rr)
        mv[et][rr] = lrelu(acc[ct][et][rr] + bc[rr]);
    #pragma unroll
    for (int hh = 0; hh < 8; ++hh) {
      f32x4 w = *(const f32x4*)&A2l[hh][chb];
      #pragma unroll
      for (int et = 0; et < 4; ++et)
        part[et][hh] += mv[et][0] * w[0] + mv[et][1] * w[1] +
                        mv[et][2] * w[2] + mv[et][3] * w[3];
    }
  }
  // reduce across quads in-wave, then cross-wave via LDS atomics
  #pragma unroll
  for (int et = 0; et < 4; ++et)
    #pragma unroll
    for (int hh = 0; hh < 8; ++hh) {
      part[et][hh] += __shfl_xor(part[et][hh], 16);
      part[et][hh] += __shfl_xor(part[et][hh], 32);
    }
  if (quad == 0) {
    #pragma unroll
    for (int et = 0; et < 4; ++et) {
      int e = et * 16 + l15;
      #pragma unroll
      for (int hh = 0; hh < 8; ++hh)
        atomicAdd(&pl[e][hh], part[et][hh]);
    }
  }
  __syncthreads();
  if (t < 64) {
    f32x4 t0 = *(const f32x4*)&pl[t][0];
    f32x4 t1 = *(const f32x4*)&pl[t][4];
    const f32x4 a20 = *(const f32x4*)a2g;
    const f32x4 a21 = *(const f32x4*)(a2g + 4);
    float sacc = 0.f;
    #pragma unroll
    for (int j = 0; j < 4; ++j) {
      sacc += lrelu(t0[j] + a20[j]);
      sacc += lrelu(t1[j] + a21[j]);
    }
    float p = __expf(sacc * 0.125f);
    __builtin_nontemporal_store(p, &Pp[eb + t]);
    #pragma unroll
    for (int d = 1; d < 64; d <<= 1) p += __shfl_xor(p, d);
    if (t == 0) Zblk[wg] = p;   // plain store — no atomics
  }
}

// ---------------------------------------------------------------------------
// K5 per-node accumulate + residual + LayerNorm; reduces Zblk[4096] per WG
// (L2-broadcast), fp8 v gathers, 4 nodes/WG.
// ---------------------------------------------------------------------------
__global__ __launch_bounds__(256) void scatter_ln_kernel(
    const int* __restrict__ startA, const float* __restrict__ Pp,
    const float* __restrict__ Zblk, const int2* __restrict__ st2,
    const uint8_t* __restrict__ vq, const unsigned short* __restrict__ hbuf,
    const float* __restrict__ gamma, const float* __restrict__ beta,
    float* __restrict__ out)
{
  __shared__ float zsl[4];
  const int t = threadIdx.x;
  const int wid = t >> 6, lane = t & 63;
  const int n = blockIdx.x * 4 + wid;
  // reduce Zblk[4096]
  float zp = 0.f;
  {
    const f32x4* zb = (const f32x4*)Zblk;
    #pragma unroll
    for (int i = 0; i < 4; ++i) {
      f32x4 v = zb[t * 4 + i];
      zp += v[0] + v[1] + v[2] + v[3];
    }
  }
  #pragma unroll
  for (int d = 1; d < 64; d <<= 1) zp += __shfl_xor(zp, d);
  if (lane == 0) zsl[wid] = zp;
  __syncthreads();
  const float invZ = 1.f / (zsl[0] + zsl[1] + zsl[2] + zsl[3]);

  const int s0 = startA[n], s1 = startA[n + 1];
  float a0 = 0.f, a1_ = 0.f, a2_ = 0.f, a3_ = 0.f;
  int i = s0;
  for (; i + 3 < s1; i += 4) {
    float w0 = Pp[i], w1 = Pp[i + 1], w2 = Pp[i + 2], w3 = Pp[i + 3];
    int t0 = st2[i].y, t1 = st2[i + 1].y, t2 = st2[i + 2].y, t3 = st2[i + 3].y;
    uint32_t e0 = *(const uint32_t*)(vq + (size_t)t0 * 256 + lane * 4);
    uint32_t e1 = *(const uint32_t*)(vq + (size_t)t1 * 256 + lane * 4);
    uint32_t e2 = *(const uint32_t*)(vq + (size_t)t2 * 256 + lane * 4);
    uint32_t e3 = *(const uint32_t*)(vq + (size_t)t3 * 256 + lane * 4);
    float f0[4], f1[4], f2[4], f3[4];
    dec4(e0, f0); dec4(e1, f1); dec4(e2, f2); dec4(e3, f3);
    a0 += w0 * f0[0] + w1 * f1[0] + w2 * f2[0] + w3 * f3[0];
    a1_ += w0 * f0[1] + w1 * f1[1] + w2 * f2[1] + w3 * f3[1];
    a2_ += w0 * f0[2] + w1 * f1[2] + w2 * f2[2] + w3 * f3[2];
    a3_ += w0 * f0[3] + w1 * f1[3] + w2 * f2[3] + w3 * f3[3];
  }
  for (; i < s1; ++i) {
    float w0 = Pp[i];
    uint32_t e0 = *(const uint32_t*)(vq + (size_t)st2[i].y * 256 + lane * 4);
    float f0[4];
    dec4(e0, f0);
    a0 += w0 * f0[0]; a1_ += w0 * f0[1]; a2_ += w0 * f0[2]; a3_ += w0 * f0[3];
  }
  a0 *= invZ; a1_ *= invZ; a2_ *= invZ; a3_ *= invZ;
  u16x4 hv = __builtin_nontemporal_load(
      (const u16x4*)(hbuf + (size_t)n * 256 + lane * 4));
  float x0 = bf2f(hv[0]) + a0, x1 = bf2f(hv[1]) + a1_;
  float x2 = bf2f(hv[2]) + a2_, x3 = bf2f(hv[3]) + a3_;
  float sum = x0 + x1 + x2 + x3;
  float sq = x0 * x0 + x1 * x1 + x2 * x2 + x3 * x3;
  #pragma unroll
  for (int d = 1; d < 64; d <<= 1) { sum += __shfl_xor(sum, d); sq += __shfl_xor(sq, d); }
  float mu = sum * (1.f / 256.f);
  float var = sq * (1.f / 256.f) - mu * mu;
  float rstd = rsqrtf(var + 1e-5f);
  f32x4 g = *(const f32x4*)(gamma + lane * 4);
  f32x4 b = *(const f32x4*)(beta + lane * 4);
  f32x4 o;
  o[0] = (x0 - mu) * rstd * g[0] + b[0];
  o[1] = (x1 - mu) * rstd * g[1] + b[1];
  o[2] = (x2 - mu) * rstd * g[2] + b[2];
  o[3] = (x3 - mu) * rstd * g[3] + b[3];
  *(f32x4*)(out + (size_t)n * 256 + lane * 4) = o;
}

extern "C" void kernel_launch(void* const* d_in, const int* in_sizes, int n_in,
                              void* d_out, int out_size, void* d_ws, size_t ws_size,
                              hipStream_t stream)
{
  (void)in_sizes; (void)n_in; (void)out_size; (void)ws_size;
  const float* nf    = (const float*)d_in[0];
  const int*   eidx  = (const int*)  d_in[1];
  const float* ef    = (const float*)d_in[2];
  const float* Wn    = (const float*)d_in[3];
  const float* bn    = (const float*)d_in[4];
  const float* Wq    = (const float*)d_in[5];
  const float* bq    = (const float*)d_in[6];
  const float* Wk    = (const float*)d_in[7];
  const float* bk    = (const float*)d_in[8];
  const float* Wv    = (const float*)d_in[9];
  const float* bv    = (const float*)d_in[10];
  const float* We    = (const float*)d_in[11];
  const float* be    = (const float*)d_in[12];
  const float* A1    = (const float*)d_in[13];
  const float* a1    = (const float*)d_in[14];
  const float* A2    = (const float*)d_in[15];
  const float* a2    = (const float*)d_in[16];
  const float* gamma = (const float*)d_in[17];
  const float* beta  = (const float*)d_in[18];
  float* out = (float*)d_out;

  char* ws = (char*)d_ws;
  size_t off = 0;
  auto take = [&](size_t bytes) {
    size_t r = off; off += (bytes + 255) & ~(size_t)255; return r;
  };
  int*   deg     = (int*)  (ws + take((size_t)NN * 4));   // memset below
  int*   startA  = (int*)  (ws + take((size_t)(NN + 1) * 4));
  int*   cursor  = (int*)  (ws + take((size_t)NN * 4));
  int*   perm    = (int*)  (ws + take((size_t)EE * 4));
  int2*  st2     = (int2*) (ws + take((size_t)EE * 8));
  float* Pp      = (float*)(ws + take((size_t)EE * 4));
  float* Zblk    = (float*)(ws + take(4096 * 4));
  unsigned short* hbuf = (unsigned short*)(ws + take((size_t)NN * DD * 2));
  uint8_t* vqB   = (uint8_t*)(ws + take((size_t)NN * DD));
  uint8_t* QaB   = (uint8_t*)(ws + take((size_t)NN * DD));
  uint8_t* KaB   = (uint8_t*)(ws + take((size_t)NN * DD));
  unsigned short* BcatT = (unsigned short*)(ws + take((size_t)1024 * 256 * 2));
  float* bcat    = (float*)(ws + take(1024 * 4));
  unsigned short* WeaT  = (unsigned short*)(ws + take((size_t)256 * 64 * 2));
  float* bcomb   = (float*)(ws + take(256 * 4));
  float* A2p     = (float*)(ws + take(256 * 8 * 4));
  unsigned short* nfb   = (unsigned short*)(ws + take((size_t)NN * DD * 2));

  // zero deg (at ws start)
  (void)hipMemsetAsync(d_ws, 0, (size_t)NN * 4, stream);

  prep_hist_kernel<<<1731, 256, 0, stream>>>(Wn, bn, Wq, bq, Wk, bk, Wv, bv,
                                             We, be, A1, a1, A2, eidx,
                                             BcatT, bcat, WeaT, bcomb, A2p, deg);
  conv_scan_kernel<<<2049, 256, 0, stream>>>(nf, nfb, deg, startA, cursor);
  gemm_perm_kernel<<<2048, 256, 0, stream>>>(nfb, BcatT, bcat, hbuf, vqB,
                                             QaB, KaB, eidx, cursor,
                                             perm, st2);
  edge_scores_kernel<<<4096, 256, 0, stream>>>(perm, st2, ef, QaB, KaB,
                                               WeaT, bcomb, A2p, a2, Pp, Zblk);
  scatter_ln_kernel<<<NN / 4, 256, 0, stream>>>(startA, Pp, Zblk, st2,
                                                vqB, hbuf, gamma, beta, out);
}